// Round 1
// baseline (161.127 us; speedup 1.0000x reference)
//
#include <hip/hip_runtime.h>

#define PI_F 3.14159265358979323846f

// ---------- helpers ----------

__device__ __forceinline__ float fast_tanh(float x) {
    // tanh(x) = 1 - 2/(exp(2x)+1); stable for large |x| (exp->inf -> 1, exp->0 -> -1)
    float e = __expf(2.0f * x);
    return 1.0f - 2.0f / (e + 1.0f);
}

__device__ __forceinline__ float bfly_sum(float v) {
#pragma unroll
    for (int d = 1; d < 64; d <<= 1) v += __shfl_xor(v, d, 64);
    return v;
}

// qubit i <-> bit (5-i) of lane index; mask m = 32 >> i

__device__ __forceinline__ void gate_ry(float& re, float& im, int lane, int m, float c, float s) {
    float pre = __shfl_xor(re, m, 64);
    float pim = __shfl_xor(im, m, 64);
    float sg = (lane & m) ? s : -s;
    re = fmaf(c, re, sg * pre);
    im = fmaf(c, im, sg * pim);
}

__device__ __forceinline__ void gate_rx(float& re, float& im, int lane, int m, float c, float s) {
    // [[c, -i s],[-i s, c]]: new = c*a - i*s*p  (bit-independent)
    float pre = __shfl_xor(re, m, 64);
    float pim = __shfl_xor(im, m, 64);
    float nre = fmaf(c, re, s * pim);
    float nim = fmaf(c, im, -s * pre);
    re = nre; im = nim;
}

__device__ __forceinline__ void gate_rz(float& re, float& im, int lane, int m, float c, float s) {
    // bit0: *(c - i s); bit1: *(c + i s)
    float sg = (lane & m) ? s : -s;
    float nre = fmaf(c, re, -sg * im);
    float nim = fmaf(c, im, sg * re);
    re = nre; im = nim;
}

__device__ __forceinline__ void gate_cnot(float& re, float& im, int lane, int mc, int mt) {
    float pre = __shfl_xor(re, mt, 64);
    float pim = __shfl_xor(im, mt, 64);
    re = (lane & mc) ? pre : re;
    im = (lane & mc) ? pim : im;
}

__device__ __forceinline__ void gate_cry(float& re, float& im, int lane, int mc, int mt, float c, float s) {
    float pre = __shfl_xor(re, mt, 64);
    float pim = __shfl_xor(im, mt, 64);
    float sg = (lane & mt) ? s : -s;
    float nre = fmaf(c, re, sg * pre);
    float nim = fmaf(c, im, sg * pim);
    re = (lane & mc) ? nre : re;
    im = (lane & mc) ? nim : im;
}

// per-modality dot: lane handles k = lane + 64*it; W transposed in LDS [6][D]
template<int D>
__device__ __forceinline__ void dot6(const float* __restrict__ f, const float* __restrict__ sw,
                                     int lane, float dots[6]) {
    constexpr int IT = D / 64;
    float x[IT];
#pragma unroll
    for (int it = 0; it < IT; ++it) x[it] = f[it * 64 + lane];
    float acc[6];
#pragma unroll
    for (int j = 0; j < 6; ++j) acc[j] = 0.f;
#pragma unroll
    for (int it = 0; it < IT; ++it) {
#pragma unroll
        for (int j = 0; j < 6; ++j)
            acc[j] = fmaf(x[it], sw[j * D + it * 64 + lane], acc[j]);
    }
#pragma unroll
    for (int j = 0; j < 6; ++j) dots[j] = bfly_sum(acc[j]);
}

#define D0 768
#define D1 512
#define D2 1024
#define BASE1 (6 * D0)
#define BASE2 (6 * D0 + 6 * D1)
#define LDS_FLOATS (6 * (D0 + D1 + D2))

__global__ __launch_bounds__(512, 2) void qf_kernel(
    const float* __restrict__ f0, const float* __restrict__ W0, const float* __restrict__ b0,
    const float* __restrict__ f1, const float* __restrict__ W1, const float* __restrict__ b1,
    const float* __restrict__ f2, const float* __restrict__ W2, const float* __restrict__ b2,
    const float* __restrict__ qw, const float* __restrict__ fl,
    float* __restrict__ out)
{
    __shared__ float sWT[LDS_FLOATS];  // 54 KB: [6][D] per modality, transposed

    // stage W transposed (lane-stride-1 reads later -> conflict-free)
#pragma unroll
    for (int j = 0; j < 6; ++j) {
        for (int k = threadIdx.x; k < D0; k += 512) sWT[j * D0 + k] = W0[k * 6 + j];
        for (int k = threadIdx.x; k < D1; k += 512) sWT[BASE1 + j * D1 + k] = W1[k * 6 + j];
        for (int k = threadIdx.x; k < D2; k += 512) sWT[BASE2 + j * D2 + k] = W2[k * 6 + j];
    }
    __syncthreads();

    const int lane = threadIdx.x & 63;
    const int wv = blockIdx.x * 8 + (threadIdx.x >> 6);  // 4096 waves total

    // fusion softmax (3 logits)
    float l0 = fl[0], l1 = fl[1], l2 = fl[2];
    float mx = fmaxf(l0, fmaxf(l1, l2));
    float e0 = __expf(l0 - mx), e1 = __expf(l1 - mx), e2 = __expf(l2 - mx);
    float inv = 1.0f / (e0 + e1 + e2);
    float fw0 = e0 * inv, fw1 = e1 * inv, fw2 = e2 * inv;

    // fixed-rotation gate constants (hoisted once per wave; unrolled -> registers)
    float crx[12], srx[12], cryv[12], sryv[12], crz[12], srz[12];
#pragma unroll
    for (int g = 0; g < 12; ++g) {
        __sincosf(qw[g * 3 + 0] * 0.5f, &srx[g], &crx[g]);
        __sincosf(qw[g * 3 + 1] * 0.5f, &sryv[g], &cryv[g]);
        __sincosf(qw[g * 3 + 2] * 0.5f, &srz[g], &crz[g]);
    }

    for (int s = 0; s < 4; ++s) {
        const int b = wv + s * 4096;

        // ---------- phase 1: angles ----------
        float dots[6], ang[6];

        dot6<D0>(f0 + (size_t)b * D0, sWT, lane, dots);
#pragma unroll
        for (int j = 0; j < 6; ++j) ang[j] = fw0 * fast_tanh(dots[j] + b0[j]);

        dot6<D1>(f1 + (size_t)b * D1, sWT + BASE1, lane, dots);
#pragma unroll
        for (int j = 0; j < 6; ++j) ang[j] += fw1 * fast_tanh(dots[j] + b1[j]);

        dot6<D2>(f2 + (size_t)b * D2, sWT + BASE2, lane, dots);
#pragma unroll
        for (int j = 0; j < 6; ++j) ang[j] = PI_F * (ang[j] + fw2 * fast_tanh(dots[j] + b2[j]));

        // ---------- phase 2: 6-qubit circuit, lane = basis state ----------
        float re = (lane == 0) ? 1.0f : 0.0f;
        float im = 0.0f;

        // encoding RY(angles[i]) on wire i
#pragma unroll
        for (int i = 0; i < 6; ++i) {
            float c, sn;
            __sincosf(0.5f * ang[i], &sn, &c);
            gate_ry(re, im, lane, 32 >> i, c, sn);
        }

#pragma unroll
        for (int l = 0; l < 2; ++l) {
#pragma unroll
            for (int i = 0; i < 6; ++i) {
                const int g = l * 6 + i;
                const int m = 32 >> i;
                gate_rx(re, im, lane, m, crx[g], srx[g]);
                gate_ry(re, im, lane, m, cryv[g], sryv[g]);
                gate_rz(re, im, lane, m, crz[g], srz[g]);
            }
            // CNOT chain + ring closure
#pragma unroll
            for (int i = 0; i < 5; ++i)
                gate_cnot(re, im, lane, 32 >> i, 32 >> (i + 1));
            gate_cnot(re, im, lane, 32, 1);
            // CRY on (0,1),(2,3),(4,5) with theta = qw[l][i][1]
            gate_cry(re, im, lane, 32, 16, cryv[l * 6 + 0], sryv[l * 6 + 0]);
            gate_cry(re, im, lane, 8, 4, cryv[l * 6 + 2], sryv[l * 6 + 2]);
            gate_cry(re, im, lane, 2, 1, cryv[l * 6 + 4], sryv[l * 6 + 4]);
        }

        // ---------- measurement: z_i = sum_l p_l * (bit_i ? -1 : +1) ----------
        float p = fmaf(re, re, im * im);
        float zsel = 0.0f;
#pragma unroll
        for (int i = 0; i < 6; ++i) {
            const int m = 32 >> i;
            float v = (lane & m) ? -p : p;
            v = bfly_sum(v);
            if (lane == i) zsel = v;
        }
        if (lane < 6) out[(size_t)b * 6 + lane] = zsel;
    }
}

extern "C" void kernel_launch(void* const* d_in, const int* in_sizes, int n_in,
                              void* d_out, int out_size, void* d_ws, size_t ws_size,
                              hipStream_t stream) {
    const float* f0 = (const float*)d_in[0];
    const float* W0 = (const float*)d_in[1];
    const float* b0 = (const float*)d_in[2];
    const float* f1 = (const float*)d_in[3];
    const float* W1 = (const float*)d_in[4];
    const float* b1 = (const float*)d_in[5];
    const float* f2 = (const float*)d_in[6];
    const float* W2 = (const float*)d_in[7];
    const float* b2 = (const float*)d_in[8];
    const float* qw = (const float*)d_in[9];
    const float* fl = (const float*)d_in[10];
    float* out = (float*)d_out;

    qf_kernel<<<512, 512, 0, stream>>>(f0, W0, b0, f1, W1, b1, f2, W2, b2, qw, fl, out);
}

// Round 2
// 67.448 us; speedup vs baseline: 2.3889x; 2.3889x over previous
//
#include <hip/hip_runtime.h>

#define PI_F 3.14159265358979323846f

// ---------------- cross-lane primitives ----------------

template<int CTRL>
__device__ __forceinline__ float dppmov(float v) {
    // returns src permuted by DPP ctrl (old=0 unused: all lanes enabled)
    return __int_as_float(__builtin_amdgcn_update_dpp(0, __float_as_int(v), CTRL, 0xF, 0xF, true));
}
template<int PAT>
__device__ __forceinline__ float swzf(float v) {
    return __int_as_float(__builtin_amdgcn_ds_swizzle(__float_as_int(v), PAT));
}

// partner value at lane ^ M
template<int M>
__device__ __forceinline__ float xsh(float v) {
    if constexpr (M == 1)       return dppmov<0xB1>(v);   // quad_perm [1,0,3,2]
    else if constexpr (M == 2)  return dppmov<0x4E>(v);   // quad_perm [2,3,0,1]
    else if constexpr (M == 4)  return swzf<0x101F>(v);   // ds_swizzle xor 4
    else if constexpr (M == 8)  return dppmov<0x128>(v);  // row_ror:8 == xor 8
    else if constexpr (M == 16) return swzf<0x401F>(v);   // ds_swizzle xor 16
    else                        return __shfl_xor(v, 32, 64);
}

__device__ __forceinline__ float pl16_sum(float v) {
#if __has_builtin(__builtin_amdgcn_permlane16_swap)
    auto r = __builtin_amdgcn_permlane16_swap(__float_as_uint(v), __float_as_uint(v), false, false);
    return __uint_as_float(r[0]) + __uint_as_float(r[1]);
#else
    return v + swzf<0x401F>(v);
#endif
}
__device__ __forceinline__ float pl32_sum(float v) {
#if __has_builtin(__builtin_amdgcn_permlane32_swap)
    auto r = __builtin_amdgcn_permlane32_swap(__float_as_uint(v), __float_as_uint(v), false, false);
    return __uint_as_float(r[0]) + __uint_as_float(r[1]);
#else
    return v + __shfl_xor(v, 32, 64);
#endif
}

// full 64-lane sum, replicated to all lanes; only ONE DS op (mask 4)
__device__ __forceinline__ float bfly_sum(float v) {
    v += dppmov<0xB1>(v);     // xor 1  (VALU)
    v += dppmov<0x4E>(v);     // xor 2  (VALU)
    v += swzf<0x101F>(v);     // xor 4  (DS)
    v += dppmov<0x128>(v);    // xor 8  (VALU)
    v = pl16_sum(v);          // xor 16 (VALU)
    v = pl32_sum(v);          // xor 32 (VALU)
    return v;
}

__device__ __forceinline__ float fast_tanh(float x) {
    float e = __expf(2.0f * x);
    return 1.0f - 2.0f / (e + 1.0f);
}

// ---------------- 4-sample GEMV (W^T staged in LDS, b128 reads) ----------------

template<int D>
__device__ __forceinline__ void gemv4(const float4* __restrict__ f4, const float4* __restrict__ w4,
                                      int lane, float acc[4][6]) {
    constexpr int CH = D / 256;
    constexpr int RD = D / 4;
#pragma unroll
    for (int s = 0; s < 4; ++s)
#pragma unroll
        for (int j = 0; j < 6; ++j) acc[s][j] = 0.0f;
#pragma unroll 2
    for (int ch = 0; ch < CH; ++ch) {
        float4 x0 = f4[0 * RD + ch * 64 + lane];
        float4 x1 = f4[1 * RD + ch * 64 + lane];
        float4 x2 = f4[2 * RD + ch * 64 + lane];
        float4 x3 = f4[3 * RD + ch * 64 + lane];
#pragma unroll
        for (int j = 0; j < 6; ++j) {
            float4 w = w4[j * RD + ch * 64 + lane];
            acc[0][j] = fmaf(x0.x, w.x, fmaf(x0.y, w.y, fmaf(x0.z, w.z, fmaf(x0.w, w.w, acc[0][j]))));
            acc[1][j] = fmaf(x1.x, w.x, fmaf(x1.y, w.y, fmaf(x1.z, w.z, fmaf(x1.w, w.w, acc[1][j]))));
            acc[2][j] = fmaf(x2.x, w.x, fmaf(x2.y, w.y, fmaf(x2.z, w.z, fmaf(x2.w, w.w, acc[2][j]))));
            acc[3][j] = fmaf(x3.x, w.x, fmaf(x3.y, w.y, fmaf(x3.z, w.z, fmaf(x3.w, w.w, acc[3][j]))));
        }
    }
}

// ---------------- quantum gates, 4 states per wave, lane = basis state ----------------
// qubit i <-> lane bit (5-i); mask = 32>>i

// general single-qubit U = [[u00, u01],[-conj(u01), conj(u00)]]
template<int M>
__device__ __forceinline__ void gateU(float (&re)[4], float (&im)[4], int lane,
                                      float ar, float ai, float br, float bi) {
    const bool hi = (lane & M) != 0;
    const float Ai = hi ? -ai : ai;   // coeff on own amp: (ar, Ai)
    const float Br = hi ? -br : br;   // coeff on partner: (Br, bi)
#pragma unroll
    for (int s = 0; s < 4; ++s) {
        float pre = xsh<M>(re[s]);
        float pim = xsh<M>(im[s]);
        float nr = ar * re[s] - Ai * im[s] + Br * pre - bi * pim;
        float ni = ar * im[s] + Ai * re[s] + Br * pim + bi * pre;
        re[s] = nr; im[s] = ni;
    }
}

template<int MC, int MT>
__device__ __forceinline__ void gateCNOT(float (&re)[4], float (&im)[4], int lane) {
    const bool c1 = (lane & MC) != 0;
#pragma unroll
    for (int s = 0; s < 4; ++s) {
        float pre = xsh<MT>(re[s]);
        float pim = xsh<MT>(im[s]);
        re[s] = c1 ? pre : re[s];
        im[s] = c1 ? pim : im[s];
    }
}

template<int MC, int MT>
__device__ __forceinline__ void gateCRY(float (&re)[4], float (&im)[4], int lane, float c, float sn) {
    const bool c1 = (lane & MC) != 0;
    const float sg = (lane & MT) ? sn : -sn;
#pragma unroll
    for (int s = 0; s < 4; ++s) {
        float pre = xsh<MT>(re[s]);
        float pim = xsh<MT>(im[s]);
        float nr = fmaf(c, re[s], sg * pre);
        float ni = fmaf(c, im[s], sg * pim);
        re[s] = c1 ? nr : re[s];
        im[s] = c1 ? ni : im[s];
    }
}

// encoding RY with per-sample angle (column I of ang)
template<int I>
__device__ __forceinline__ void encRY(float (&re)[4], float (&im)[4], int lane,
                                      const float (&ang)[4][6]) {
    constexpr int M = 32 >> I;
#pragma unroll
    for (int s = 0; s < 4; ++s) {
        float c, sn;
        __sincosf(0.5f * ang[s][I], &sn, &c);
        float pre = xsh<M>(re[s]);
        float pim = xsh<M>(im[s]);
        float sg = (lane & M) ? sn : -sn;
        re[s] = fmaf(c, re[s], sg * pre);
        im[s] = fmaf(c, im[s], sg * pim);
    }
}

// layer rotation RX(a)->RY(b)->RZ(g) fused into one SU(2) gate, consts from uniform qw loads
template<int L, int I>
__device__ __forceinline__ void rotLayer(float (&re)[4], float (&im)[4], int lane,
                                         const float* __restrict__ qw) {
    constexpr int M = 32 >> I;
    constexpr int G = (L * 6 + I) * 3;
    float a = qw[G + 0], b = qw[G + 1], g = qw[G + 2];
    float ca, sa, cb, sb, cc, sc;
    __sincosf(0.5f * a, &sa, &ca);
    __sincosf(0.5f * b, &sb, &cb);
    __sincosf(0.5f * g, &sc, &cc);
    // Ry*Rx: m00 = (cb*ca, sb*sa); m01 = (-sb*ca, -cb*sa)
    float m00r = cb * ca, m00i = sb * sa;
    float m01r = -sb * ca, m01i = -cb * sa;
    // U = Rz * (Ry*Rx): row0 scaled by (cc - i sc)
    float u00r = m00r * cc + m00i * sc, u00i = m00i * cc - m00r * sc;
    float u01r = m01r * cc + m01i * sc, u01i = m01i * cc - m01r * sc;
    gateU<M>(re, im, lane, u00r, u00i, u01r, u01i);
}

template<int L, int I>
__device__ __forceinline__ void cryLayer(float (&re)[4], float (&im)[4], int lane,
                                         const float* __restrict__ qw) {
    constexpr int MC = 32 >> I;
    constexpr int MT = 16 >> I;
    float c, sn;
    __sincosf(0.5f * qw[(L * 6 + I) * 3 + 1], &sn, &c);
    gateCRY<MC, MT>(re, im, lane, c, sn);
}

// ---------------- main kernel ----------------

#define D0 768
#define D1 512
#define D2 1024
#define BASE1 (6 * D0)
#define BASE2 (6 * D0 + 6 * D1)
#define LDS_FLOATS (6 * (D0 + D1 + D2))

__global__ __launch_bounds__(512, 4) void qf_kernel(
    const float* __restrict__ f0, const float* __restrict__ W0, const float* __restrict__ b0,
    const float* __restrict__ f1, const float* __restrict__ W1, const float* __restrict__ b1,
    const float* __restrict__ f2, const float* __restrict__ W2, const float* __restrict__ b2,
    const float* __restrict__ qw, const float* __restrict__ fl,
    float* __restrict__ out)
{
    __shared__ __align__(16) float sWT[LDS_FLOATS];  // 54 KB: [6][D] per modality, transposed

#pragma unroll
    for (int j = 0; j < 6; ++j) {
        for (int k = threadIdx.x; k < D0; k += 512) sWT[j * D0 + k] = W0[k * 6 + j];
        for (int k = threadIdx.x; k < D1; k += 512) sWT[BASE1 + j * D1 + k] = W1[k * 6 + j];
        for (int k = threadIdx.x; k < D2; k += 512) sWT[BASE2 + j * D2 + k] = W2[k * 6 + j];
    }
    __syncthreads();

    const int lane = threadIdx.x & 63;
    const int wave = blockIdx.x * 8 + (threadIdx.x >> 6);  // 4096 waves
    const int base = wave * 4;                             // 4 samples per wave

    // fusion softmax (uniform)
    float l0 = fl[0], l1 = fl[1], l2 = fl[2];
    float mx = fmaxf(l0, fmaxf(l1, l2));
    float e0 = __expf(l0 - mx), e1 = __expf(l1 - mx), e2 = __expf(l2 - mx);
    float inv = 1.0f / (e0 + e1 + e2);
    float fw0 = e0 * inv, fw1 = e1 * inv, fw2 = e2 * inv;

    float acc[4][6], ang[4][6];

    // ---- phase 1: angles = PI * sum_m fw_m * tanh(feat_m @ W_m + b_m) ----
    gemv4<D0>((const float4*)(f0 + (size_t)base * D0), (const float4*)sWT, lane, acc);
#pragma unroll
    for (int s = 0; s < 4; ++s)
#pragma unroll
        for (int j = 0; j < 6; ++j)
            ang[s][j] = fw0 * fast_tanh(bfly_sum(acc[s][j]) + b0[j]);

    gemv4<D1>((const float4*)(f1 + (size_t)base * D1), (const float4*)(sWT + BASE1), lane, acc);
#pragma unroll
    for (int s = 0; s < 4; ++s)
#pragma unroll
        for (int j = 0; j < 6; ++j)
            ang[s][j] += fw1 * fast_tanh(bfly_sum(acc[s][j]) + b1[j]);

    gemv4<D2>((const float4*)(f2 + (size_t)base * D2), (const float4*)(sWT + BASE2), lane, acc);
#pragma unroll
    for (int s = 0; s < 4; ++s)
#pragma unroll
        for (int j = 0; j < 6; ++j)
            ang[s][j] = PI_F * (ang[s][j] + fw2 * fast_tanh(bfly_sum(acc[s][j]) + b2[j]));

    // ---- phase 2: 6-qubit circuit on 4 states, lane = basis state ----
    float re[4], im[4];
#pragma unroll
    for (int s = 0; s < 4; ++s) { re[s] = (lane == 0) ? 1.0f : 0.0f; im[s] = 0.0f; }

    encRY<0>(re, im, lane, ang); encRY<1>(re, im, lane, ang); encRY<2>(re, im, lane, ang);
    encRY<3>(re, im, lane, ang); encRY<4>(re, im, lane, ang); encRY<5>(re, im, lane, ang);

    // layer 0
    rotLayer<0,0>(re, im, lane, qw); rotLayer<0,1>(re, im, lane, qw); rotLayer<0,2>(re, im, lane, qw);
    rotLayer<0,3>(re, im, lane, qw); rotLayer<0,4>(re, im, lane, qw); rotLayer<0,5>(re, im, lane, qw);
    gateCNOT<32,16>(re, im, lane); gateCNOT<16,8>(re, im, lane); gateCNOT<8,4>(re, im, lane);
    gateCNOT<4,2>(re, im, lane);  gateCNOT<2,1>(re, im, lane);  gateCNOT<32,1>(re, im, lane);
    cryLayer<0,0>(re, im, lane, qw); cryLayer<0,2>(re, im, lane, qw); cryLayer<0,4>(re, im, lane, qw);

    // layer 1
    rotLayer<1,0>(re, im, lane, qw); rotLayer<1,1>(re, im, lane, qw); rotLayer<1,2>(re, im, lane, qw);
    rotLayer<1,3>(re, im, lane, qw); rotLayer<1,4>(re, im, lane, qw); rotLayer<1,5>(re, im, lane, qw);
    gateCNOT<32,16>(re, im, lane); gateCNOT<16,8>(re, im, lane); gateCNOT<8,4>(re, im, lane);
    gateCNOT<4,2>(re, im, lane);  gateCNOT<2,1>(re, im, lane);  gateCNOT<32,1>(re, im, lane);
    cryLayer<1,0>(re, im, lane, qw); cryLayer<1,2>(re, im, lane, qw); cryLayer<1,4>(re, im, lane, qw);

    // ---- measurement: FWHT over 64 lanes; lane (32>>i) holds z_i ----
#pragma unroll
    for (int s = 0; s < 4; ++s) {
        float p = fmaf(re[s], re[s], im[s] * im[s]);
        {
            float q = xsh<1>(p);  p = (lane & 1)  ? (q - p) : (p + q);
            q = xsh<2>(p);        p = (lane & 2)  ? (q - p) : (p + q);
            q = xsh<4>(p);        p = (lane & 4)  ? (q - p) : (p + q);
            q = xsh<8>(p);        p = (lane & 8)  ? (q - p) : (p + q);
            q = xsh<16>(p);       p = (lane & 16) ? (q - p) : (p + q);
            q = xsh<32>(p);       p = (lane & 32) ? (q - p) : (p + q);
        }
        if (__popc(lane) == 1)
            out[(size_t)(base + s) * 6 + (6 - __ffs(lane))] = p;
    }
}

extern "C" void kernel_launch(void* const* d_in, const int* in_sizes, int n_in,
                              void* d_out, int out_size, void* d_ws, size_t ws_size,
                              hipStream_t stream) {
    const float* f0 = (const float*)d_in[0];
    const float* W0 = (const float*)d_in[1];
    const float* b0 = (const float*)d_in[2];
    const float* f1 = (const float*)d_in[3];
    const float* W1 = (const float*)d_in[4];
    const float* b1 = (const float*)d_in[5];
    const float* f2 = (const float*)d_in[6];
    const float* W2 = (const float*)d_in[7];
    const float* b2 = (const float*)d_in[8];
    const float* qw = (const float*)d_in[9];
    const float* fl = (const float*)d_in[10];
    float* out = (float*)d_out;

    qf_kernel<<<512, 512, 0, stream>>>(f0, W0, b0, f1, W1, b1, f2, W2, b2, qw, fl, out);
}

// Round 3
// 53.127 us; speedup vs baseline: 3.0329x; 1.2696x over previous
//
#include <hip/hip_runtime.h>

#define PI_F 3.14159265358979323846f

// ---------------- W^T layout in d_ws (floats) ----------------
#define WT0_OFF 0
#define WT1_OFF 4608
#define WT2_OFF 7680
#define WT_FLOATS 13824

__global__ void wt_kernel(const float* __restrict__ W0, const float* __restrict__ W1,
                          const float* __restrict__ W2, float* __restrict__ wt) {
    int t = blockIdx.x * 256 + threadIdx.x;  // grid 54*256 = 13824
    if (t < 4608) {
        int j = t / 768, k = t - j * 768;
        wt[WT0_OFF + t] = W0[k * 6 + j];
    } else if (t < 7680) {
        int u = t - 4608; int j = u / 512, k = u - j * 512;
        wt[WT1_OFF + u] = W1[k * 6 + j];
    } else if (t < WT_FLOATS) {
        int u = t - 7680; int j = u / 1024, k = u - j * 1024;
        wt[WT2_OFF + u] = W2[k * 6 + j];
    }
}

// ---------------- cross-lane primitives ----------------

template<int CTRL>
__device__ __forceinline__ float dppmov(float v) {
    return __int_as_float(__builtin_amdgcn_update_dpp(0, __float_as_int(v), CTRL, 0xF, 0xF, true));
}
template<int PAT>
__device__ __forceinline__ float swzf(float v) {
    return __int_as_float(__builtin_amdgcn_ds_swizzle(__float_as_int(v), PAT));
}

template<int M>
__device__ __forceinline__ float xsh(float v) {
    if constexpr (M == 1)       return dppmov<0xB1>(v);   // quad_perm [1,0,3,2]
    else if constexpr (M == 2)  return dppmov<0x4E>(v);   // quad_perm [2,3,0,1]
    else if constexpr (M == 4)  return swzf<0x101F>(v);   // ds_swizzle xor 4
    else if constexpr (M == 8)  return dppmov<0x128>(v);  // row_ror:8 == xor 8
    else if constexpr (M == 16) return swzf<0x401F>(v);   // ds_swizzle xor 16
    else                        return __shfl_xor(v, 32, 64);
}

__device__ __forceinline__ float pl16_sum(float v) {
#if __has_builtin(__builtin_amdgcn_permlane16_swap)
    auto r = __builtin_amdgcn_permlane16_swap(__float_as_uint(v), __float_as_uint(v), false, false);
    return __uint_as_float(r[0]) + __uint_as_float(r[1]);
#else
    return v + swzf<0x401F>(v);
#endif
}
__device__ __forceinline__ float pl32_sum(float v) {
#if __has_builtin(__builtin_amdgcn_permlane32_swap)
    auto r = __builtin_amdgcn_permlane32_swap(__float_as_uint(v), __float_as_uint(v), false, false);
    return __uint_as_float(r[0]) + __uint_as_float(r[1]);
#else
    return v + __shfl_xor(v, 32, 64);
#endif
}

// full 64-lane sum broadcast; one DS op
__device__ __forceinline__ float bfly_sum(float v) {
    v += dppmov<0xB1>(v);
    v += dppmov<0x4E>(v);
    v += swzf<0x101F>(v);
    v += dppmov<0x128>(v);
    v = pl16_sum(v);
    v = pl32_sum(v);
    return v;
}

__device__ __forceinline__ float fast_tanh(float x) {
    float e = __expf(2.0f * x);
    return 1.0f - 2.0f / (e + 1.0f);
}

// ---------------- 2-sample GEMV, W^T from global (L2-resident), pipelined ----------------

template<int D>
__device__ __forceinline__ void gemv2(const float* __restrict__ f, const float* __restrict__ wt,
                                      int lane, float acc[2][6]) {
    constexpr int CH = D / 256;
    constexpr int RD = D / 4;
    const float4* __restrict__ x0 = (const float4*)f;
    const float4* __restrict__ x1 = (const float4*)(f + D);
    const float4* __restrict__ w4 = (const float4*)wt;
    float4 a0 = x0[lane];
    float4 a1 = x1[lane];
#pragma unroll
    for (int j = 0; j < 6; ++j) { acc[0][j] = 0.0f; acc[1][j] = 0.0f; }
#pragma unroll
    for (int ch = 0; ch < CH; ++ch) {
        float4 n0 = a0, n1 = a1;
        if (ch + 1 < CH) {
            n0 = x0[(ch + 1) * 64 + lane];
            n1 = x1[(ch + 1) * 64 + lane];
        }
#pragma unroll
        for (int j = 0; j < 6; ++j) {
            float4 w = w4[j * RD + ch * 64 + lane];
            acc[0][j] = fmaf(a0.x, w.x, fmaf(a0.y, w.y, fmaf(a0.z, w.z, fmaf(a0.w, w.w, acc[0][j]))));
            acc[1][j] = fmaf(a1.x, w.x, fmaf(a1.y, w.y, fmaf(a1.z, w.z, fmaf(a1.w, w.w, acc[1][j]))));
        }
        a0 = n0; a1 = n1;
    }
}

// ---------------- quantum gates, 2 states per wave, lane = basis state ----------------
// qubit i <-> lane bit (5-i); mask = 32>>i

template<int M>
__device__ __forceinline__ void gateU(float (&re)[2], float (&im)[2], int lane,
                                      float ar, float ai, float br, float bi) {
    const bool hi = (lane & M) != 0;
    const float Ai = hi ? -ai : ai;
    const float Br = hi ? -br : br;
#pragma unroll
    for (int s = 0; s < 2; ++s) {
        float pre = xsh<M>(re[s]);
        float pim = xsh<M>(im[s]);
        float nr = ar * re[s] - Ai * im[s] + Br * pre - bi * pim;
        float ni = ar * im[s] + Ai * re[s] + Br * pim + bi * pre;
        re[s] = nr; im[s] = ni;
    }
}

template<int MC, int MT>
__device__ __forceinline__ void gateCNOT(float (&re)[2], float (&im)[2], int lane) {
    const bool c1 = (lane & MC) != 0;
#pragma unroll
    for (int s = 0; s < 2; ++s) {
        float pre = xsh<MT>(re[s]);
        float pim = xsh<MT>(im[s]);
        re[s] = c1 ? pre : re[s];
        im[s] = c1 ? pim : im[s];
    }
}

template<int MC, int MT>
__device__ __forceinline__ void gateCRY(float (&re)[2], float (&im)[2], int lane, float c, float sn) {
    const bool c1 = (lane & MC) != 0;
    const float sg = (lane & MT) ? sn : -sn;
#pragma unroll
    for (int s = 0; s < 2; ++s) {
        float pre = xsh<MT>(re[s]);
        float pim = xsh<MT>(im[s]);
        float nr = fmaf(c, re[s], sg * pre);
        float ni = fmaf(c, im[s], sg * pim);
        re[s] = c1 ? nr : re[s];
        im[s] = c1 ? ni : im[s];
    }
}

template<int L, int I>
__device__ __forceinline__ void rotLayer(float (&re)[2], float (&im)[2], int lane,
                                         const float* __restrict__ qw) {
    constexpr int M = 32 >> I;
    constexpr int G = (L * 6 + I) * 3;
    float a = qw[G + 0], b = qw[G + 1], g = qw[G + 2];
    float ca, sa, cb, sb, cc, sc;
    __sincosf(0.5f * a, &sa, &ca);
    __sincosf(0.5f * b, &sb, &cb);
    __sincosf(0.5f * g, &sc, &cc);
    float m00r = cb * ca, m00i = sb * sa;
    float m01r = -sb * ca, m01i = -cb * sa;
    float u00r = m00r * cc + m00i * sc, u00i = m00i * cc - m00r * sc;
    float u01r = m01r * cc + m01i * sc, u01i = m01i * cc - m01r * sc;
    gateU<M>(re, im, lane, u00r, u00i, u01r, u01i);
}

template<int L, int I>
__device__ __forceinline__ void cryLayer(float (&re)[2], float (&im)[2], int lane,
                                         const float* __restrict__ qw) {
    constexpr int MC = 32 >> I;
    constexpr int MT = 16 >> I;
    float c, sn;
    __sincosf(0.5f * qw[(L * 6 + I) * 3 + 1], &sn, &c);
    gateCRY<MC, MT>(re, im, lane, c, sn);
}

// ---------------- main kernel: no LDS, 2 samples per wave ----------------

#define D0 768
#define D1 512
#define D2 1024

__global__ __launch_bounds__(256, 6) void qf_main(
    const float* __restrict__ f0, const float* __restrict__ b0,
    const float* __restrict__ f1, const float* __restrict__ b1,
    const float* __restrict__ f2, const float* __restrict__ b2,
    const float* __restrict__ qw, const float* __restrict__ fl,
    const float* __restrict__ wt, float* __restrict__ out)
{
    const int lane = threadIdx.x & 63;
    const int wave = blockIdx.x * 4 + (threadIdx.x >> 6);  // 8192 waves
    const int s0 = wave * 2;                               // samples s0, s0+1

    // fusion softmax (uniform scalars)
    float l0 = fl[0], l1 = fl[1], l2 = fl[2];
    float mx = fmaxf(l0, fmaxf(l1, l2));
    float e0 = __expf(l0 - mx), e1 = __expf(l1 - mx), e2 = __expf(l2 - mx);
    float inv = 1.0f / (e0 + e1 + e2);
    float fw0 = e0 * inv, fw1 = e1 * inv, fw2 = e2 * inv;

    float acc[2][6], ang[2][6];

    // ---- phase 1: angles ----
    gemv2<D0>(f0 + (size_t)s0 * D0, wt + WT0_OFF, lane, acc);
#pragma unroll
    for (int s = 0; s < 2; ++s)
#pragma unroll
        for (int j = 0; j < 6; ++j)
            ang[s][j] = fw0 * fast_tanh(bfly_sum(acc[s][j]) + b0[j]);

    gemv2<D1>(f1 + (size_t)s0 * D1, wt + WT1_OFF, lane, acc);
#pragma unroll
    for (int s = 0; s < 2; ++s)
#pragma unroll
        for (int j = 0; j < 6; ++j)
            ang[s][j] += fw1 * fast_tanh(bfly_sum(acc[s][j]) + b1[j]);

    gemv2<D2>(f2 + (size_t)s0 * D2, wt + WT2_OFF, lane, acc);
#pragma unroll
    for (int s = 0; s < 2; ++s)
#pragma unroll
        for (int j = 0; j < 6; ++j)
            ang[s][j] = PI_F * (ang[s][j] + fw2 * fast_tanh(bfly_sum(acc[s][j]) + b2[j]));

    // ---- phase 2: encoding is a real product state (no shuffles) ----
    float re[2], im[2];
#pragma unroll
    for (int s = 0; s < 2; ++s) {
        float amp = 1.0f;
#pragma unroll
        for (int i = 0; i < 6; ++i) {
            float c, sn;
            __sincosf(0.5f * ang[s][i], &sn, &c);
            amp *= (lane & (32 >> i)) ? sn : c;
        }
        re[s] = amp;
        im[s] = 0.0f;
    }

    // layer 0
    rotLayer<0,0>(re, im, lane, qw); rotLayer<0,1>(re, im, lane, qw); rotLayer<0,2>(re, im, lane, qw);
    rotLayer<0,3>(re, im, lane, qw); rotLayer<0,4>(re, im, lane, qw); rotLayer<0,5>(re, im, lane, qw);
    gateCNOT<32,16>(re, im, lane); gateCNOT<16,8>(re, im, lane); gateCNOT<8,4>(re, im, lane);
    gateCNOT<4,2>(re, im, lane);  gateCNOT<2,1>(re, im, lane);  gateCNOT<32,1>(re, im, lane);
    cryLayer<0,0>(re, im, lane, qw); cryLayer<0,2>(re, im, lane, qw); cryLayer<0,4>(re, im, lane, qw);

    // layer 1
    rotLayer<1,0>(re, im, lane, qw); rotLayer<1,1>(re, im, lane, qw); rotLayer<1,2>(re, im, lane, qw);
    rotLayer<1,3>(re, im, lane, qw); rotLayer<1,4>(re, im, lane, qw); rotLayer<1,5>(re, im, lane, qw);
    gateCNOT<32,16>(re, im, lane); gateCNOT<16,8>(re, im, lane); gateCNOT<8,4>(re, im, lane);
    gateCNOT<4,2>(re, im, lane);  gateCNOT<2,1>(re, im, lane);  gateCNOT<32,1>(re, im, lane);
    cryLayer<1,0>(re, im, lane, qw); cryLayer<1,2>(re, im, lane, qw); cryLayer<1,4>(re, im, lane, qw);

    // ---- measurement: FWHT; lane (32>>i) holds z_i ----
#pragma unroll
    for (int s = 0; s < 2; ++s) {
        float p = fmaf(re[s], re[s], im[s] * im[s]);
        float q;
        q = xsh<1>(p);  p = (lane & 1)  ? (q - p) : (p + q);
        q = xsh<2>(p);  p = (lane & 2)  ? (q - p) : (p + q);
        q = xsh<4>(p);  p = (lane & 4)  ? (q - p) : (p + q);
        q = xsh<8>(p);  p = (lane & 8)  ? (q - p) : (p + q);
        q = xsh<16>(p); p = (lane & 16) ? (q - p) : (p + q);
        q = xsh<32>(p); p = (lane & 32) ? (q - p) : (p + q);
        if (__popc(lane) == 1)
            out[(size_t)(s0 + s) * 6 + (6 - __ffs(lane))] = p;
    }
}

extern "C" void kernel_launch(void* const* d_in, const int* in_sizes, int n_in,
                              void* d_out, int out_size, void* d_ws, size_t ws_size,
                              hipStream_t stream) {
    const float* f0 = (const float*)d_in[0];
    const float* W0 = (const float*)d_in[1];
    const float* b0 = (const float*)d_in[2];
    const float* f1 = (const float*)d_in[3];
    const float* W1 = (const float*)d_in[4];
    const float* b1 = (const float*)d_in[5];
    const float* f2 = (const float*)d_in[6];
    const float* W2 = (const float*)d_in[7];
    const float* b2 = (const float*)d_in[8];
    const float* qw = (const float*)d_in[9];
    const float* fl = (const float*)d_in[10];
    float* out = (float*)d_out;
    float* wt = (float*)d_ws;  // 13824 floats = 55296 B

    wt_kernel<<<54, 256, 0, stream>>>(W0, W1, W2, wt);
    qf_main<<<2048, 256, 0, stream>>>(f0, b0, f1, b1, f2, b2, qw, fl, wt, out);
}

// Round 4
// 48.370 us; speedup vs baseline: 3.3311x; 1.0983x over previous
//
#include <hip/hip_runtime.h>

#define PI_F 3.14159265358979323846f

#define D0 768
#define D1 512
#define D2 1024
#define WT_FLOATS 13824
#define U_OFF   WT_FLOATS          // 12 gates * 4 floats (u00r,u00i,u01r,u01i)
#define CRY_OFF (WT_FLOATS + 48)   // 6 * 2 floats (c,s)

// ---------------- prep: W^T transpose + uniform gate constants ----------------

__global__ void prep_kernel(const float* __restrict__ W0, const float* __restrict__ W1,
                            const float* __restrict__ W2, const float* __restrict__ qw,
                            float* __restrict__ ws) {
    int t = blockIdx.x * 256 + threadIdx.x;
    if (t < 4608) {
        int j = t / 768, k = t - j * 768;
        ws[t] = W0[k * 6 + j];
    } else if (t < 7680) {
        int u = t - 4608, j = u / 512, k = u - j * 512;
        ws[t] = W1[k * 6 + j];
    } else if (t < WT_FLOATS) {
        int u = t - 7680, j = u / 1024, k = u - j * 1024;
        ws[t] = W2[k * 6 + j];
    } else if (t < WT_FLOATS + 12) {
        int g = t - WT_FLOATS;  // g = layer*6 + qubit
        float ca, sa, cb, sb, cc, sc;
        sincosf(0.5f * qw[g * 3 + 0], &sa, &ca);
        sincosf(0.5f * qw[g * 3 + 1], &sb, &cb);
        sincosf(0.5f * qw[g * 3 + 2], &sc, &cc);
        // U = Rz(g) * Ry(b) * Rx(a); SU(2): row0 = (u00, u01)
        float m00r = cb * ca, m00i = sb * sa;
        float m01r = -sb * ca, m01i = -cb * sa;
        float* u4 = ws + U_OFF + g * 4;
        u4[0] = m00r * cc + m00i * sc;
        u4[1] = m00i * cc - m00r * sc;
        u4[2] = m01r * cc + m01i * sc;
        u4[3] = m01i * cc - m01r * sc;
    } else if (t < WT_FLOATS + 18) {
        int k = t - WT_FLOATS - 12;   // k = layer*3 + pair
        int l = k / 3, i = (k - l * 3) * 2;
        float c, s;
        sincosf(0.5f * qw[(l * 6 + i) * 3 + 1], &s, &c);
        ws[CRY_OFF + k * 2 + 0] = c;
        ws[CRY_OFF + k * 2 + 1] = s;
    }
}

// ---------------- cross-lane primitives ----------------

template<int CTRL>
__device__ __forceinline__ float dppmov(float v) {
    return __int_as_float(__builtin_amdgcn_update_dpp(0, __float_as_int(v), CTRL, 0xF, 0xF, true));
}
template<int PAT>
__device__ __forceinline__ float swzf(float v) {
    return __int_as_float(__builtin_amdgcn_ds_swizzle(__float_as_int(v), PAT));
}

template<int M>
__device__ __forceinline__ float xsh(float v) {
    if constexpr (M == 1)       return dppmov<0xB1>(v);   // quad_perm [1,0,3,2]
    else if constexpr (M == 2)  return dppmov<0x4E>(v);   // quad_perm [2,3,0,1]
    else if constexpr (M == 4)  return swzf<0x101F>(v);   // ds_swizzle xor 4
    else if constexpr (M == 8)  return dppmov<0x128>(v);  // row_ror:8 == xor 8
    else if constexpr (M == 16) return swzf<0x401F>(v);   // ds_swizzle xor 16
    else                        return __shfl_xor(v, 32, 64);
}

__device__ __forceinline__ float pl16_sum(float v) {
#if __has_builtin(__builtin_amdgcn_permlane16_swap)
    auto r = __builtin_amdgcn_permlane16_swap(__float_as_uint(v), __float_as_uint(v), false, false);
    return __uint_as_float(r[0]) + __uint_as_float(r[1]);
#else
    return v + swzf<0x401F>(v);
#endif
}
__device__ __forceinline__ float pl32_sum(float v) {
#if __has_builtin(__builtin_amdgcn_permlane32_swap)
    auto r = __builtin_amdgcn_permlane32_swap(__float_as_uint(v), __float_as_uint(v), false, false);
    return __uint_as_float(r[0]) + __uint_as_float(r[1]);
#else
    return v + __shfl_xor(v, 32, 64);
#endif
}

__device__ __forceinline__ float bfly_sum(float v) {
    v += dppmov<0xB1>(v);
    v += dppmov<0x4E>(v);
    v += swzf<0x101F>(v);
    v += dppmov<0x128>(v);
    v = pl16_sum(v);
    v = pl32_sum(v);
    return v;
}

__device__ __forceinline__ float fast_tanh(float x) {
    float e = __expf(2.0f * x);
    return 1.0f - 2.0f / (e + 1.0f);
}

__device__ __forceinline__ float dot4(float4 a, float4 w, float acc) {
    return fmaf(a.x, w.x, fmaf(a.y, w.y, fmaf(a.z, w.z, fmaf(a.w, w.w, acc))));
}

// ---------------- gates (2 states/wave, lane = basis state; qubit i <-> bit 5-i) ----------------

template<int M>
__device__ __forceinline__ void gateU(float (&re)[2], float (&im)[2], int lane,
                                      float ar, float ai, float br, float bi) {
    const bool hi = (lane & M) != 0;
    const float Ai = hi ? -ai : ai;
    const float Br = hi ? -br : br;
#pragma unroll
    for (int s = 0; s < 2; ++s) {
        float pre = xsh<M>(re[s]);
        float pim = xsh<M>(im[s]);
        float nr = ar * re[s] - Ai * im[s] + Br * pre - bi * pim;
        float ni = ar * im[s] + Ai * re[s] + Br * pim + bi * pre;
        re[s] = nr; im[s] = ni;
    }
}

template<int MC, int MT>
__device__ __forceinline__ void gateCRY(float (&re)[2], float (&im)[2], int lane, float c, float sn) {
    const bool c1 = (lane & MC) != 0;
    const float sg = (lane & MT) ? sn : -sn;
#pragma unroll
    for (int s = 0; s < 2; ++s) {
        float pre = xsh<MT>(re[s]);
        float pim = xsh<MT>(im[s]);
        float nr = fmaf(c, re[s], sg * pre);
        float ni = fmaf(c, im[s], sg * pim);
        re[s] = c1 ? nr : re[s];
        im[s] = c1 ? ni : im[s];
    }
}

template<int I>
__device__ __forceinline__ void l1gate(float (&re)[2], float (&im)[2], int lane,
                                       const float* __restrict__ ws) {
    constexpr int M = 32 >> I;
    const float ar = ws[U_OFF + (6 + I) * 4 + 0];
    const float ai = ws[U_OFF + (6 + I) * 4 + 1];
    const float br = ws[U_OFF + (6 + I) * 4 + 2];
    const float bi = ws[U_OFF + (6 + I) * 4 + 3];
    gateU<M>(re, im, lane, ar, ai, br, bi);
}

template<int L, int P>
__device__ __forceinline__ void cryGate(float (&re)[2], float (&im)[2], int lane,
                                        const float* __restrict__ ws) {
    constexpr int MC = 32 >> (2 * P);
    constexpr int MT = 16 >> (2 * P);
    const float c = ws[CRY_OFF + (L * 3 + P) * 2 + 0];
    const float s = ws[CRY_OFF + (L * 3 + P) * 2 + 1];
    gateCRY<MC, MT>(re, im, lane, c, s);
}

// encoding RY(ang) followed by layer-0 RX/RY/RZ: still a product state -> build directly
__device__ __forceinline__ void buildState(const float (&ang)[6], int lane,
                                           const float* __restrict__ ws,
                                           float& reO, float& imO) {
    float pr, pi;
#pragma unroll
    for (int i = 0; i < 6; ++i) {
        float cq, sq;
        __sincosf(0.5f * ang[i], &sq, &cq);
        const float ar = ws[U_OFF + i * 4 + 0];
        const float ai = ws[U_OFF + i * 4 + 1];
        const float br = ws[U_OFF + i * 4 + 2];
        const float bi = ws[U_OFF + i * 4 + 3];
        // v = U * (cq, sq)^T ; lo = u00*c+u01*s, hi = u10*c+u11*s with u10=-conj(u01), u11=conj(u00)
        float vloR = ar * cq + br * sq;
        float vloI = ai * cq + bi * sq;
        float vhiR = ar * sq - br * cq;
        float vhiI = bi * cq - ai * sq;
        bool hi = (lane & (32 >> i)) != 0;
        float vr = hi ? vhiR : vloR;
        float vi = hi ? vhiI : vloI;
        if (i == 0) { pr = vr; pi = vi; }
        else { float t = pr * vr - pi * vi; pi = pr * vi + pi * vr; pr = t; }
    }
    reO = pr; imO = pi;
}

// ---------------- main kernel ----------------

__global__ __launch_bounds__(256, 3) void qf_main(
    const float* __restrict__ f0, const float* __restrict__ b0,
    const float* __restrict__ f1, const float* __restrict__ b1,
    const float* __restrict__ f2, const float* __restrict__ b2,
    const float* __restrict__ fl, const float* __restrict__ ws,
    float* __restrict__ out)
{
    const int lane = threadIdx.x & 63;
    const int wave = blockIdx.x * 4 + (threadIdx.x >> 6);  // 8192 waves
    const int s0 = wave * 2;

    // ---- issue ALL feature loads up-front (18 outstanding 16B loads/lane) ----
    const float4* __restrict__ xA0 = (const float4*)(f0 + (size_t)s0 * D0);
    const float4* __restrict__ xB0 = (const float4*)(f0 + (size_t)(s0 + 1) * D0);
    const float4* __restrict__ xA1 = (const float4*)(f1 + (size_t)s0 * D1);
    const float4* __restrict__ xB1 = (const float4*)(f1 + (size_t)(s0 + 1) * D1);
    const float4* __restrict__ xA2 = (const float4*)(f2 + (size_t)s0 * D2);
    const float4* __restrict__ xB2 = (const float4*)(f2 + (size_t)(s0 + 1) * D2);

    float4 xa0 = xA0[lane], xa1 = xA0[64 + lane], xa2 = xA0[128 + lane];
    float4 xb0 = xB0[lane], xb1 = xB0[64 + lane], xb2 = xB0[128 + lane];
    float4 xa3 = xA1[lane], xa4 = xA1[64 + lane];
    float4 xb3 = xB1[lane], xb4 = xB1[64 + lane];
    float4 xa5 = xA2[lane], xa6 = xA2[64 + lane], xa7 = xA2[128 + lane], xa8 = xA2[192 + lane];
    float4 xb5 = xB2[lane], xb6 = xB2[64 + lane], xb7 = xB2[128 + lane], xb8 = xB2[192 + lane];

    // fusion softmax (uniform)
    float l0 = fl[0], l1 = fl[1], l2 = fl[2];
    float mx = fmaxf(l0, fmaxf(l1, l2));
    float e0 = __expf(l0 - mx), e1 = __expf(l1 - mx), e2 = __expf(l2 - mx);
    float inv = 1.0f / (e0 + e1 + e2);
    float fw0 = e0 * inv, fw1 = e1 * inv, fw2 = e2 * inv;

    const float4* __restrict__ w4 = (const float4*)ws;
    float accA[6], accB[6];
    float angA[6], angB[6];

    // ---- modality 0 (768 dims, 3 chunks; W^T float4 base j*192) ----
#pragma unroll
    for (int j = 0; j < 6; ++j) {
        float4 w0 = w4[j * 192 + lane];
        float4 w1 = w4[j * 192 + 64 + lane];
        float4 w2 = w4[j * 192 + 128 + lane];
        float a = 0.f, b = 0.f;
        a = dot4(xa0, w0, a); a = dot4(xa1, w1, a); a = dot4(xa2, w2, a);
        b = dot4(xb0, w0, b); b = dot4(xb1, w1, b); b = dot4(xb2, w2, b);
        accA[j] = a; accB[j] = b;
    }
#pragma unroll
    for (int j = 0; j < 6; ++j) {
        angA[j] = fw0 * fast_tanh(bfly_sum(accA[j]) + b0[j]);
        angB[j] = fw0 * fast_tanh(bfly_sum(accB[j]) + b0[j]);
    }

    // ---- modality 1 (512 dims, 2 chunks; base 1152 + j*128) ----
#pragma unroll
    for (int j = 0; j < 6; ++j) {
        float4 w0 = w4[1152 + j * 128 + lane];
        float4 w1 = w4[1152 + j * 128 + 64 + lane];
        float a = 0.f, b = 0.f;
        a = dot4(xa3, w0, a); a = dot4(xa4, w1, a);
        b = dot4(xb3, w0, b); b = dot4(xb4, w1, b);
        accA[j] = a; accB[j] = b;
    }
#pragma unroll
    for (int j = 0; j < 6; ++j) {
        angA[j] += fw1 * fast_tanh(bfly_sum(accA[j]) + b1[j]);
        angB[j] += fw1 * fast_tanh(bfly_sum(accB[j]) + b1[j]);
    }

    // ---- modality 2 (1024 dims, 4 chunks; base 1920 + j*256) ----
#pragma unroll
    for (int j = 0; j < 6; ++j) {
        float4 w0 = w4[1920 + j * 256 + lane];
        float4 w1 = w4[1920 + j * 256 + 64 + lane];
        float4 w2 = w4[1920 + j * 256 + 128 + lane];
        float4 w3 = w4[1920 + j * 256 + 192 + lane];
        float a = 0.f, b = 0.f;
        a = dot4(xa5, w0, a); a = dot4(xa6, w1, a); a = dot4(xa7, w2, a); a = dot4(xa8, w3, a);
        b = dot4(xb5, w0, b); b = dot4(xb6, w1, b); b = dot4(xb7, w2, b); b = dot4(xb8, w3, b);
        accA[j] = a; accB[j] = b;
    }
#pragma unroll
    for (int j = 0; j < 6; ++j) {
        angA[j] = PI_F * (angA[j] + fw2 * fast_tanh(bfly_sum(accA[j]) + b2[j]));
        angB[j] = PI_F * (angB[j] + fw2 * fast_tanh(bfly_sum(accB[j]) + b2[j]));
    }

    // ---- circuit ----
    // CNOT chain (both layers identical) collapses to one lane permutation:
    // sigma = l ^ ((l>>1)&0x1F) ^ ((l>>5)&1)
    const int sigma = lane ^ ((lane >> 1) & 0x1F) ^ ((lane >> 5) & 1);

    float re[2], im[2];
    buildState(angA, lane, ws, re[0], im[0]);  // encoding + layer-0 rotations fused
    buildState(angB, lane, ws, re[1], im[1]);

    // layer 0 tail: CNOT chain as one permutation, then CRYs
    re[0] = __shfl(re[0], sigma, 64); im[0] = __shfl(im[0], sigma, 64);
    re[1] = __shfl(re[1], sigma, 64); im[1] = __shfl(im[1], sigma, 64);
    cryGate<0,0>(re, im, lane, ws); cryGate<0,1>(re, im, lane, ws); cryGate<0,2>(re, im, lane, ws);

    // layer 1: rotations (uniform precomputed U), CNOT permutation, CRYs
    l1gate<0>(re, im, lane, ws); l1gate<1>(re, im, lane, ws); l1gate<2>(re, im, lane, ws);
    l1gate<3>(re, im, lane, ws); l1gate<4>(re, im, lane, ws); l1gate<5>(re, im, lane, ws);
    re[0] = __shfl(re[0], sigma, 64); im[0] = __shfl(im[0], sigma, 64);
    re[1] = __shfl(re[1], sigma, 64); im[1] = __shfl(im[1], sigma, 64);
    cryGate<1,0>(re, im, lane, ws); cryGate<1,1>(re, im, lane, ws); cryGate<1,2>(re, im, lane, ws);

    // ---- measurement: FWHT; lane (32>>i) holds z_i ----
#pragma unroll
    for (int s = 0; s < 2; ++s) {
        float p = fmaf(re[s], re[s], im[s] * im[s]);
        float q;
        q = xsh<1>(p);  p = (lane & 1)  ? (q - p) : (p + q);
        q = xsh<2>(p);  p = (lane & 2)  ? (q - p) : (p + q);
        q = xsh<4>(p);  p = (lane & 4)  ? (q - p) : (p + q);
        q = xsh<8>(p);  p = (lane & 8)  ? (q - p) : (p + q);
        q = xsh<16>(p); p = (lane & 16) ? (q - p) : (p + q);
        q = xsh<32>(p); p = (lane & 32) ? (q - p) : (p + q);
        if (__popc(lane) == 1)
            out[(size_t)(s0 + s) * 6 + (6 - __ffs(lane))] = p;
    }
}

extern "C" void kernel_launch(void* const* d_in, const int* in_sizes, int n_in,
                              void* d_out, int out_size, void* d_ws, size_t ws_size,
                              hipStream_t stream) {
    const float* f0 = (const float*)d_in[0];
    const float* W0 = (const float*)d_in[1];
    const float* b0 = (const float*)d_in[2];
    const float* f1 = (const float*)d_in[3];
    const float* W1 = (const float*)d_in[4];
    const float* b1 = (const float*)d_in[5];
    const float* f2 = (const float*)d_in[6];
    const float* W2 = (const float*)d_in[7];
    const float* b2 = (const float*)d_in[8];
    const float* qw = (const float*)d_in[9];
    const float* fl = (const float*)d_in[10];
    float* out = (float*)d_out;
    float* ws = (float*)d_ws;  // 13842 floats used

    prep_kernel<<<55, 256, 0, stream>>>(W0, W1, W2, qw, ws);
    qf_main<<<2048, 256, 0, stream>>>(f0, b0, f1, b1, f2, b2, fl, ws, out);
}

// Round 5
// 46.386 us; speedup vs baseline: 3.4736x; 1.0428x over previous
//
#include <hip/hip_runtime.h>

#define PI_F 3.14159265358979323846f

#define D0 768
#define D1 512
#define D2 1024
#define WT_FLOATS 13824
#define U_OFF   WT_FLOATS          // 12 gates * 4 floats (u00r,u00i,u01r,u01i)
#define CRY_OFF (WT_FLOATS + 48)   // 6 * 2 floats (c,s)

// ---------------- prep: W^T transpose + uniform gate constants ----------------

__global__ void prep_kernel(const float* __restrict__ W0, const float* __restrict__ W1,
                            const float* __restrict__ W2, const float* __restrict__ qw,
                            float* __restrict__ ws) {
    int t = blockIdx.x * 256 + threadIdx.x;
    if (t < 4608) {
        int j = t / 768, k = t - j * 768;
        ws[t] = W0[k * 6 + j];
    } else if (t < 7680) {
        int u = t - 4608, j = u / 512, k = u - j * 512;
        ws[t] = W1[k * 6 + j];
    } else if (t < WT_FLOATS) {
        int u = t - 7680, j = u / 1024, k = u - j * 1024;
        ws[t] = W2[k * 6 + j];
    } else if (t < WT_FLOATS + 12) {
        int g = t - WT_FLOATS;  // g = layer*6 + qubit
        float ca, sa, cb, sb, cc, sc;
        sincosf(0.5f * qw[g * 3 + 0], &sa, &ca);
        sincosf(0.5f * qw[g * 3 + 1], &sb, &cb);
        sincosf(0.5f * qw[g * 3 + 2], &sc, &cc);
        // U = Rz(g) * Ry(b) * Rx(a); SU(2): row0 = (u00, u01)
        float m00r = cb * ca, m00i = sb * sa;
        float m01r = -sb * ca, m01i = -cb * sa;
        float* u4 = ws + U_OFF + g * 4;
        u4[0] = m00r * cc + m00i * sc;
        u4[1] = m00i * cc - m00r * sc;
        u4[2] = m01r * cc + m01i * sc;
        u4[3] = m01i * cc - m01r * sc;
    } else if (t < WT_FLOATS + 18) {
        int k = t - WT_FLOATS - 12;   // k = layer*3 + pair
        int l = k / 3, i = (k - l * 3) * 2;
        float c, s;
        sincosf(0.5f * qw[(l * 6 + i) * 3 + 1], &s, &c);
        ws[CRY_OFF + k * 2 + 0] = c;
        ws[CRY_OFF + k * 2 + 1] = s;
    }
}

// ---------------- cross-lane primitives ----------------

template<int CTRL>
__device__ __forceinline__ float dppmov(float v) {
    return __int_as_float(__builtin_amdgcn_update_dpp(0, __float_as_int(v), CTRL, 0xF, 0xF, true));
}
template<int PAT>
__device__ __forceinline__ float swzf(float v) {
    return __int_as_float(__builtin_amdgcn_ds_swizzle(__float_as_int(v), PAT));
}

template<int M>
__device__ __forceinline__ float xsh(float v) {
    if constexpr (M == 1)       return dppmov<0xB1>(v);   // quad_perm [1,0,3,2]
    else if constexpr (M == 2)  return dppmov<0x4E>(v);   // quad_perm [2,3,0,1]
    else if constexpr (M == 4)  return swzf<0x101F>(v);   // ds_swizzle xor 4
    else if constexpr (M == 8)  return dppmov<0x128>(v);  // row_ror:8 == xor 8
    else if constexpr (M == 16) return swzf<0x401F>(v);   // ds_swizzle xor 16
    else                        return __shfl_xor(v, 32, 64);
}

__device__ __forceinline__ float pl16_sum(float v) {
#if __has_builtin(__builtin_amdgcn_permlane16_swap)
    auto r = __builtin_amdgcn_permlane16_swap(__float_as_uint(v), __float_as_uint(v), false, false);
    return __uint_as_float(r[0]) + __uint_as_float(r[1]);
#else
    return v + swzf<0x401F>(v);
#endif
}
__device__ __forceinline__ float pl32_sum(float v) {
#if __has_builtin(__builtin_amdgcn_permlane32_swap)
    auto r = __builtin_amdgcn_permlane32_swap(__float_as_uint(v), __float_as_uint(v), false, false);
    return __uint_as_float(r[0]) + __uint_as_float(r[1]);
#else
    return v + __shfl_xor(v, 32, 64);
#endif
}

__device__ __forceinline__ float fast_tanh(float x) {
    float e = __expf(2.0f * x);
    return 1.0f - 2.0f / (e + 1.0f);
}

__device__ __forceinline__ float dot4(float4 a, float4 w, float acc) {
    return fmaf(a.x, w.x, fmaf(a.y, w.y, fmaf(a.z, w.z, fmaf(a.w, w.w, acc))));
}

// ---------------- gates (2 states/wave, lane = basis state; qubit i <-> bit 5-i) ----------------

template<int M>
__device__ __forceinline__ void gateU(float (&re)[2], float (&im)[2], int lane,
                                      float ar, float ai, float br, float bi) {
    const bool hi = (lane & M) != 0;
    const float Ai = hi ? -ai : ai;
    const float Br = hi ? -br : br;
#pragma unroll
    for (int s = 0; s < 2; ++s) {
        float pre = xsh<M>(re[s]);
        float pim = xsh<M>(im[s]);
        float nr = ar * re[s] - Ai * im[s] + Br * pre - bi * pim;
        float ni = ar * im[s] + Ai * re[s] + Br * pim + bi * pre;
        re[s] = nr; im[s] = ni;
    }
}

template<int MC, int MT>
__device__ __forceinline__ void gateCRY(float (&re)[2], float (&im)[2], int lane, float c, float sn) {
    const bool c1 = (lane & MC) != 0;
    const float sg = (lane & MT) ? sn : -sn;
#pragma unroll
    for (int s = 0; s < 2; ++s) {
        float pre = xsh<MT>(re[s]);
        float pim = xsh<MT>(im[s]);
        float nr = fmaf(c, re[s], sg * pre);
        float ni = fmaf(c, im[s], sg * pim);
        re[s] = c1 ? nr : re[s];
        im[s] = c1 ? ni : im[s];
    }
}

template<int I>
__device__ __forceinline__ void l1gate(float (&re)[2], float (&im)[2], int lane,
                                       const float* __restrict__ ws) {
    constexpr int M = 32 >> I;
    const float ar = ws[U_OFF + (6 + I) * 4 + 0];
    const float ai = ws[U_OFF + (6 + I) * 4 + 1];
    const float br = ws[U_OFF + (6 + I) * 4 + 2];
    const float bi = ws[U_OFF + (6 + I) * 4 + 3];
    gateU<M>(re, im, lane, ar, ai, br, bi);
}

template<int L, int P>
__device__ __forceinline__ void cryGate(float (&re)[2], float (&im)[2], int lane,
                                        const float* __restrict__ ws) {
    constexpr int MC = 32 >> (2 * P);
    constexpr int MT = 16 >> (2 * P);
    const float c = ws[CRY_OFF + (L * 3 + P) * 2 + 0];
    const float s = ws[CRY_OFF + (L * 3 + P) * 2 + 1];
    gateCRY<MC, MT>(re, im, lane, c, s);
}

// encoding RY(ang) followed by layer-0 RX/RY/RZ: product state -> build directly
__device__ __forceinline__ void buildState(const float (&ang)[6], int lane,
                                           const float* __restrict__ ws,
                                           float& reO, float& imO) {
    float pr, pi;
#pragma unroll
    for (int i = 0; i < 6; ++i) {
        float cq, sq;
        __sincosf(0.5f * ang[i], &sq, &cq);
        const float ar = ws[U_OFF + i * 4 + 0];
        const float ai = ws[U_OFF + i * 4 + 1];
        const float br = ws[U_OFF + i * 4 + 2];
        const float bi = ws[U_OFF + i * 4 + 3];
        float vloR = ar * cq + br * sq;
        float vloI = ai * cq + bi * sq;
        float vhiR = ar * sq - br * cq;
        float vhiI = bi * cq - ai * sq;
        bool hi = (lane & (32 >> i)) != 0;
        float vr = hi ? vhiR : vloR;
        float vi = hi ? vhiI : vloI;
        if (i == 0) { pr = vr; pi = vi; }
        else { float t = pr * vr - pi * vi; pi = pr * vi + pi * vr; pr = t; }
    }
    reO = pr; imO = pi;
}

// ---------------- main kernel ----------------

__global__ __launch_bounds__(256, 4) void qf_main(
    const float* __restrict__ f0, const float* __restrict__ b0,
    const float* __restrict__ f1, const float* __restrict__ b1,
    const float* __restrict__ f2, const float* __restrict__ b2,
    const float* __restrict__ fl, const float* __restrict__ ws,
    float* __restrict__ out)
{
    const int lane = threadIdx.x & 63;
    const int wave = blockIdx.x * 4 + (threadIdx.x >> 6);  // 8192 waves
    const int s0 = wave * 2;

    const float4* __restrict__ xA0 = (const float4*)(f0 + (size_t)s0 * D0);
    const float4* __restrict__ xB0 = (const float4*)(f0 + (size_t)(s0 + 1) * D0);
    const float4* __restrict__ xA1 = (const float4*)(f1 + (size_t)s0 * D1);
    const float4* __restrict__ xB1 = (const float4*)(f1 + (size_t)(s0 + 1) * D1);
    const float4* __restrict__ xA2 = (const float4*)(f2 + (size_t)s0 * D2);
    const float4* __restrict__ xB2 = (const float4*)(f2 + (size_t)(s0 + 1) * D2);

    // ---- issue m0 + m1 x-loads up-front; fence so they are NOT sunk ----
    float4 xa0 = xA0[lane], xa1 = xA0[64 + lane], xa2 = xA0[128 + lane];
    float4 xb0 = xB0[lane], xb1 = xB0[64 + lane], xb2 = xB0[128 + lane];
    float4 xa3 = xA1[lane], xa4 = xA1[64 + lane];
    float4 xb3 = xB1[lane], xb4 = xB1[64 + lane];
    __builtin_amdgcn_sched_barrier(0);

    // fusion softmax (uniform)
    float l0 = fl[0], l1 = fl[1], l2 = fl[2];
    float mx = fmaxf(l0, fmaxf(l1, l2));
    float e0 = __expf(l0 - mx), e1 = __expf(l1 - mx), e2 = __expf(l2 - mx);
    float inv = 1.0f / (e0 + e1 + e2);
    float fw0 = e0 * inv, fw1 = e1 * inv, fw2 = e2 * inv;

    const float4* __restrict__ w4 = (const float4*)ws;
    float r[36];  // [m][sample][j]: m0 A=0..5 B=6..11, m1 A=12..17 B=18..23, m2 A=24..29 B=30..35

    // ---- modality 0 FMAs ----
#pragma unroll
    for (int j = 0; j < 6; ++j) {
        float4 w0 = w4[j * 192 + lane];
        float4 w1 = w4[j * 192 + 64 + lane];
        float4 w2 = w4[j * 192 + 128 + lane];
        float a = 0.f, b = 0.f;
        a = dot4(xa0, w0, a); a = dot4(xa1, w1, a); a = dot4(xa2, w2, a);
        b = dot4(xb0, w0, b); b = dot4(xb1, w1, b); b = dot4(xb2, w2, b);
        r[j] = a; r[6 + j] = b;
    }

    // ---- issue m2 x-loads while m1 is still in flight ----
    float4 xa5 = xA2[lane], xa6 = xA2[64 + lane], xa7 = xA2[128 + lane], xa8 = xA2[192 + lane];
    float4 xb5 = xB2[lane], xb6 = xB2[64 + lane], xb7 = xB2[128 + lane], xb8 = xB2[192 + lane];
    __builtin_amdgcn_sched_barrier(0);

    // ---- modality 1 FMAs ----
#pragma unroll
    for (int j = 0; j < 6; ++j) {
        float4 w0 = w4[1152 + j * 128 + lane];
        float4 w1 = w4[1152 + j * 128 + 64 + lane];
        float a = 0.f, b = 0.f;
        a = dot4(xa3, w0, a); a = dot4(xa4, w1, a);
        b = dot4(xb3, w0, b); b = dot4(xb4, w1, b);
        r[12 + j] = a; r[18 + j] = b;
    }

    // ---- modality 2 FMAs ----
#pragma unroll
    for (int j = 0; j < 6; ++j) {
        float4 w0 = w4[1920 + j * 256 + lane];
        float4 w1 = w4[1920 + j * 256 + 64 + lane];
        float4 w2 = w4[1920 + j * 256 + 128 + lane];
        float4 w3 = w4[1920 + j * 256 + 192 + lane];
        float a = 0.f, b = 0.f;
        a = dot4(xa5, w0, a); a = dot4(xa6, w1, a); a = dot4(xa7, w2, a); a = dot4(xa8, w3, a);
        b = dot4(xb5, w0, b); b = dot4(xb6, w1, b); b = dot4(xb7, w2, b); b = dot4(xb8, w3, b);
        r[24 + j] = a; r[30 + j] = b;
    }

    // ---- batched 64-lane reductions: 6 passes, 36-way ILP each ----
#pragma unroll
    for (int k = 0; k < 36; ++k) r[k] += dppmov<0xB1>(r[k]);
#pragma unroll
    for (int k = 0; k < 36; ++k) r[k] += dppmov<0x4E>(r[k]);
#pragma unroll
    for (int k = 0; k < 36; ++k) r[k] += swzf<0x101F>(r[k]);
#pragma unroll
    for (int k = 0; k < 36; ++k) r[k] += dppmov<0x128>(r[k]);
#pragma unroll
    for (int k = 0; k < 36; ++k) r[k] = pl16_sum(r[k]);
#pragma unroll
    for (int k = 0; k < 36; ++k) r[k] = pl32_sum(r[k]);

    // ---- batched tanh + combine ----
    float angA[6], angB[6];
#pragma unroll
    for (int j = 0; j < 6; ++j) {
        float tA0 = fast_tanh(r[j]      + b0[j]);
        float tB0 = fast_tanh(r[6 + j]  + b0[j]);
        float tA1 = fast_tanh(r[12 + j] + b1[j]);
        float tB1 = fast_tanh(r[18 + j] + b1[j]);
        float tA2 = fast_tanh(r[24 + j] + b2[j]);
        float tB2 = fast_tanh(r[30 + j] + b2[j]);
        angA[j] = PI_F * (fw0 * tA0 + fw1 * tA1 + fw2 * tA2);
        angB[j] = PI_F * (fw0 * tB0 + fw1 * tB1 + fw2 * tB2);
    }

    // ---- circuit ----
    // CNOT chain collapses to one lane permutation: sigma = l ^ ((l>>1)&0x1F) ^ ((l>>5)&1)
    const int sigma = lane ^ ((lane >> 1) & 0x1F) ^ ((lane >> 5) & 1);

    float re[2], im[2];
    buildState(angA, lane, ws, re[0], im[0]);  // encoding + layer-0 rotations fused
    buildState(angB, lane, ws, re[1], im[1]);

    re[0] = __shfl(re[0], sigma, 64); im[0] = __shfl(im[0], sigma, 64);
    re[1] = __shfl(re[1], sigma, 64); im[1] = __shfl(im[1], sigma, 64);
    cryGate<0,0>(re, im, lane, ws); cryGate<0,1>(re, im, lane, ws); cryGate<0,2>(re, im, lane, ws);

    l1gate<0>(re, im, lane, ws); l1gate<1>(re, im, lane, ws); l1gate<2>(re, im, lane, ws);
    l1gate<3>(re, im, lane, ws); l1gate<4>(re, im, lane, ws); l1gate<5>(re, im, lane, ws);
    re[0] = __shfl(re[0], sigma, 64); im[0] = __shfl(im[0], sigma, 64);
    re[1] = __shfl(re[1], sigma, 64); im[1] = __shfl(im[1], sigma, 64);
    cryGate<1,0>(re, im, lane, ws); cryGate<1,1>(re, im, lane, ws); cryGate<1,2>(re, im, lane, ws);

    // ---- measurement: FWHT; lane (32>>i) holds z_i ----
#pragma unroll
    for (int s = 0; s < 2; ++s) {
        float p = fmaf(re[s], re[s], im[s] * im[s]);
        float q;
        q = xsh<1>(p);  p = (lane & 1)  ? (q - p) : (p + q);
        q = xsh<2>(p);  p = (lane & 2)  ? (q - p) : (p + q);
        q = xsh<4>(p);  p = (lane & 4)  ? (q - p) : (p + q);
        q = xsh<8>(p);  p = (lane & 8)  ? (q - p) : (p + q);
        q = xsh<16>(p); p = (lane & 16) ? (q - p) : (p + q);
        q = xsh<32>(p); p = (lane & 32) ? (q - p) : (p + q);
        if (__popc(lane) == 1)
            out[(size_t)(s0 + s) * 6 + (6 - __ffs(lane))] = p;
    }
}

extern "C" void kernel_launch(void* const* d_in, const int* in_sizes, int n_in,
                              void* d_out, int out_size, void* d_ws, size_t ws_size,
                              hipStream_t stream) {
    const float* f0 = (const float*)d_in[0];
    const float* W0 = (const float*)d_in[1];
    const float* b0 = (const float*)d_in[2];
    const float* f1 = (const float*)d_in[3];
    const float* W1 = (const float*)d_in[4];
    const float* b1 = (const float*)d_in[5];
    const float* f2 = (const float*)d_in[6];
    const float* W2 = (const float*)d_in[7];
    const float* b2 = (const float*)d_in[8];
    const float* qw = (const float*)d_in[9];
    const float* fl = (const float*)d_in[10];
    float* out = (float*)d_out;
    float* ws = (float*)d_ws;  // 13842 floats used

    prep_kernel<<<55, 256, 0, stream>>>(W0, W1, W2, qw, ws);
    qf_main<<<2048, 256, 0, stream>>>(f0, b0, f1, b1, f2, b2, fl, ws, out);
}